// Round 16
// baseline (113.359 us; speedup 1.0000x reference)
//
#include <hip/hip_runtime.h>
#include <hip/hip_bf16.h>
#include <math.h>

#define NH 8
#define DMv 512
#define BSv 8
#define NQv 100
#define NKv 100

typedef __attribute__((ext_vector_type(8))) short short8;
typedef __attribute__((ext_vector_type(4))) float f32x4;

__device__ __forceinline__ unsigned short bf16u(float f) {
    __hip_bfloat16 h = __float2bfloat16(f);
    return *(unsigned short*)&h;
}
__device__ __forceinline__ unsigned int pkbf(float lo, float hi) {
    return ((unsigned int)bf16u(hi) << 16) | (unsigned int)bf16u(lo);
}

// -------- Kernel 0: weight transpose + bf16 convert (+ Wc pack z==5, X->bf16 z==6..8) --------
__global__ __launch_bounds__(256) void wt_kernel(
    const float* __restrict__ W_q1, const float* __restrict__ W_q2,
    const float* __restrict__ W_k,  const float* __restrict__ W_v,
    const float* __restrict__ W_o,  const float* __restrict__ Wc,
    const float* __restrict__ xq,   const float* __restrict__ xk, const float* __restrict__ xv,
    unsigned short* __restrict__ wt, unsigned int* __restrict__ wcp,
    unsigned short* __restrict__ xbf)
{
    __shared__ float tile[64][68];
    const int z = blockIdx.z;
    const int t = threadIdx.x;
    if (z == 5) {
        if (blockIdx.x != 0 || blockIdx.y != 0) return;
        for (int i = t; i < 4096; i += 256) {
            const int m2 = i >> 6, d = i & 63;
            wcp[i] = pkbf(Wc[(size_t)(2 * m2) * 64 + d], Wc[(size_t)(2 * m2 + 1) * 64 + d]);
        }
        return;
    }
    if (z >= 6) {
        const float* xs = (z == 6) ? xq : (z == 7) ? xk : xv;
        unsigned short* xo = xbf + (size_t)(z - 6) * 409600;
        const int bid = blockIdx.y * 8 + blockIdx.x;
        for (int i = bid * 256 + t; i < 51200; i += 64 * 256) {
            float4 a = *(const float4*)(xs + (size_t)i * 8);
            float4 b = *(const float4*)(xs + (size_t)i * 8 + 4);
            uint4 w;
            w.x = pkbf(a.x, a.y); w.y = pkbf(a.z, a.w);
            w.z = pkbf(b.x, b.y); w.w = pkbf(b.z, b.w);
            *(uint4*)(xo + (size_t)i * 8) = w;
        }
        return;
    }
    const float* W = (z == 0) ? W_q1 : (z == 1) ? W_q2 : (z == 2) ? W_k : (z == 3) ? W_v : W_o;
    unsigned short* out = wt + (size_t)z * 512 * 512;
    const int k0 = blockIdx.x * 64, n0 = blockIdx.y * 64;
    const int r = t >> 2, c = t & 3;
#pragma unroll
    for (int i = 0; i < 4; i++) {
        float4 v = *(const float4*)&W[(size_t)(k0 + r) * 512 + n0 + c * 16 + i * 4];
        *(float4*)&tile[r][c * 16 + i * 4] = v;
    }
    __syncthreads();
#pragma unroll
    for (int jj = 0; jj < 4; jj++) {
        const int kb = c * 16 + jj * 4;
        ushort4 u;
        u.x = bf16u(tile[kb + 0][r]); u.y = bf16u(tile[kb + 1][r]);
        u.z = bf16u(tile[kb + 2][r]); u.w = bf16u(tile[kb + 3][r]);
        *(ushort4*)&out[(size_t)(n0 + r) * 512 + k0 + kb] = u;
    }
}

// ---------------- Kernel A: MFMA proj GEMM + bias + ELU + GroupNorm (bf16 A copy) ----------------
__global__ __launch_bounds__(256) void proj_kernel(
    const unsigned short* __restrict__ xbf,
    const unsigned short* __restrict__ wt,
    const float* __restrict__ bq1, const float* __restrict__ gq1w, const float* __restrict__ gq1b,
    const float* __restrict__ bq2, const float* __restrict__ gq2w, const float* __restrict__ gq2b,
    const float* __restrict__ bk,  const float* __restrict__ gkw,  const float* __restrict__ gkb,
    const float* __restrict__ bv,  const float* __restrict__ gvw,  const float* __restrict__ gvb,
    float* __restrict__ q1o, float* __restrict__ q2o, float* __restrict__ ko, float* __restrict__ vo)
{
    __shared__ char A_s[64 * 144];
    __shared__ char B_s[64 * 144];
    __shared__ float Y_s[64][68];

    const int p = blockIdx.z;
    const unsigned short* x;
    const float *bb, *gw, *gb;
    float* o;
    if (p == 0)      { x = xbf;           bb = bq1; gw = gq1w; gb = gq1b; o = q1o; }
    else if (p == 1) { x = xbf;           bb = bq2; gw = gq2w; gb = gq2b; o = q2o; }
    else if (p == 2) { x = xbf + 409600;  bb = bk;  gw = gkw;  gb = gkb;  o = ko;  }
    else             { x = xbf + 819200;  bb = bv;  gw = gvw;  gb = gvb;  o = vo;  }
    const unsigned short* WT = wt + (size_t)p * 512 * 512;

    const int t = threadIdx.x;
    const int r0 = blockIdx.x * 64;
    const int ct = blockIdx.y;

    const int lane = t & 63, wave = t >> 6;
    const int wr = wave >> 1, wc = wave & 1;
    const int lr = lane & 15, lq = lane >> 4;
    const int srow = t >> 2, sc = t & 3;

    f32x4 acc[2][2];
#pragma unroll
    for (int i = 0; i < 2; i++)
#pragma unroll
        for (int j = 0; j < 2; j++) acc[i][j] = (f32x4){0.f, 0.f, 0.f, 0.f};

    const int arow = (r0 + srow < 800) ? (r0 + srow) : 799;

    for (int kk = 0; kk < 8; kk++) {
        const int k0 = kk * 64;
#pragma unroll
        for (int uu = 0; uu < 2; uu++) {
            const int u = sc * 2 + uu;
            uint4 w = *(const uint4*)(x + (size_t)arow * 512 + k0 + u * 8);
            *(uint4*)(A_s + srow * 144 + u * 16) = w;
        }
#pragma unroll
        for (int uu = 0; uu < 2; uu++) {
            const int u = sc * 2 + uu;
            uint4 w = *(const uint4*)(WT + (size_t)(ct * 64 + srow) * 512 + k0 + u * 8);
            *(uint4*)(B_s + srow * 144 + u * 16) = w;
        }
        __syncthreads();
#pragma unroll
        for (int ks = 0; ks < 2; ks++) {
            short8 a0 = *(const short8*)(A_s + (wr * 32 + lr) * 144 + (ks * 4 + lq) * 16);
            short8 a1 = *(const short8*)(A_s + (wr * 32 + 16 + lr) * 144 + (ks * 4 + lq) * 16);
            short8 b0 = *(const short8*)(B_s + (wc * 32 + lr) * 144 + (ks * 4 + lq) * 16);
            short8 b1 = *(const short8*)(B_s + (wc * 32 + 16 + lr) * 144 + (ks * 4 + lq) * 16);
            acc[0][0] = __builtin_amdgcn_mfma_f32_16x16x32_bf16(a0, b0, acc[0][0], 0, 0, 0);
            acc[0][1] = __builtin_amdgcn_mfma_f32_16x16x32_bf16(a0, b1, acc[0][1], 0, 0, 0);
            acc[1][0] = __builtin_amdgcn_mfma_f32_16x16x32_bf16(a1, b0, acc[1][0], 0, 0, 0);
            acc[1][1] = __builtin_amdgcn_mfma_f32_16x16x32_bf16(a1, b1, acc[1][1], 0, 0, 0);
        }
        __syncthreads();
    }

#pragma unroll
    for (int nt = 0; nt < 2; nt++) {
        const int colL = wc * 32 + nt * 16 + lr;
        const float bias = bb[ct * 64 + colL];
#pragma unroll
        for (int mt = 0; mt < 2; mt++) {
#pragma unroll
            for (int r = 0; r < 4; r++) {
                const int row = wr * 32 + mt * 16 + lq * 4 + r;
                float y = acc[mt][nt][r] + bias;
                y = (y > 0.f) ? y : expm1f(y);
                Y_s[row][colL] = y;
            }
        }
    }
    __syncthreads();

    {
        const int row = t >> 2, c = t & 3;
        float v[16];
        float s = 0.f, ss = 0.f;
#pragma unroll
        for (int i = 0; i < 16; i++) {
            v[i] = Y_s[row][c * 16 + i];
            s += v[i]; ss += v[i] * v[i];
        }
        s += __shfl_xor(s, 1); ss += __shfl_xor(ss, 1);
        s += __shfl_xor(s, 2); ss += __shfl_xor(ss, 2);
        const float mu = s * (1.f / 64.f);
        const float var = ss * (1.f / 64.f) - mu * mu;
        const float rs = 1.0f / sqrtf(var + 1e-5f);
        const int rowg = r0 + row;
        if (rowg < 800) {
            const int b = rowg / 100, sq = rowg % 100;
            const size_t base = (((size_t)(b * NH + ct) * NQv) + sq) * 64 + c * 16;
            const int j0 = ct * 64 + c * 16;
#pragma unroll
            for (int i4 = 0; i4 < 4; i4++) {
                float4 gwv = *(const float4*)&gw[j0 + i4 * 4];
                float4 gbv = *(const float4*)&gb[j0 + i4 * 4];
                float4 ov;
                ov.x = (v[i4 * 4 + 0] - mu) * rs * gwv.x + gbv.x;
                ov.y = (v[i4 * 4 + 1] - mu) * rs * gwv.y + gbv.y;
                ov.z = (v[i4 * 4 + 2] - mu) * rs * gwv.z + gbv.z;
                ov.w = (v[i4 * 4 + 3] - mu) * rs * gwv.w + gbv.w;
                *(float4*)&o[base + i4 * 4] = ov;
            }
        }
    }
}

// ---------------- Kernel B v15: v10 per-q code, 384-thr blocks (6 waves) for 2 blocks/CU ----------------
// Model (R4-R14): LDS granularity ~64KB (max 2 blocks/CU); reg pool ~448/SIMD.
// 6-wave blocks x 2/CU = 12 waves = 3 waves/SIMD x 128 regs = 384 <= 448. Grid (8,64)=512 blocks
// = exactly 2/CU. Inner per-q code byte-identical to proven v10 (no spill at 128 regs).
__global__ __launch_bounds__(384) void attn_kernel(
    const float* __restrict__ q1g, const float* __restrict__ q2g,
    const float* __restrict__ kg, const float* __restrict__ vg,
    const float* __restrict__ Wm, const float* __restrict__ bm,
    const float* __restrict__ Ws, const float* __restrict__ bs_,
    const unsigned int* __restrict__ wcp, const float* __restrict__ bc,
    unsigned short* __restrict__ attn_v)
{
    __shared__ unsigned short Wm_s[8192];   // [128 m][64 d] bf16 swizzled
    __shared__ unsigned short K_s[6400];    // [100 k][64 d] bf16 swizzled
    __shared__ unsigned int  V_pk[3200];    // [50 k2][64 d] packed bf16 pair
    __shared__ float2 bmws_s[128];          // (b_m, W_s)
    __shared__ float p_ws[6][128];          // per-wave softmax probs
    __shared__ float pool_ws[6][128];       // per-wave pooled attn_map (x0.01)
    __shared__ float lg_ws[6][112];         // per-wave raw logits

    const int t = threadIdx.x;
    const int qt = blockIdx.x;     // 0..7
    const int bh = blockIdx.y;     // 0..63
    const int q0 = qt * 12 + ((qt < 4) ? qt : 4);   // blocks 0-3: 13 q, blocks 4-7: 12 q
    const int nq = (qt < 4) ? 13 : 12;

    const float* Kg = kg + (size_t)bh * NKv * 64;
    const float* Vg = vg + (size_t)bh * NKv * 64;

    // ---- prologue staging (single barrier) ----
    for (int i = t; i < 800; i += 384) {
        const int k = i >> 3, u = i & 7;
        float4 a = *(const float4*)(Kg + k * 64 + u * 8);
        float4 b = *(const float4*)(Kg + k * 64 + u * 8 + 4);
        uint4 w;
        w.x = pkbf(a.x, a.y); w.y = pkbf(a.z, a.w);
        w.z = pkbf(b.x, b.y); w.w = pkbf(b.z, b.w);
        *(uint4*)((char*)K_s + k * 128 + ((u ^ (k & 7)) * 16)) = w;
    }
    for (int i = t; i < 1024; i += 384) {
        const int u = i >> 7, m = i & 127;
        float f[8];
#pragma unroll
        for (int j = 0; j < 8; j++) f[j] = Wm[(size_t)(u * 8 + j) * 128 + m];
        uint4 w;
        w.x = pkbf(f[0], f[1]); w.y = pkbf(f[2], f[3]);
        w.z = pkbf(f[4], f[5]); w.w = pkbf(f[6], f[7]);
        *(uint4*)((char*)Wm_s + m * 128 + ((u ^ (m & 7)) * 16)) = w;
    }
    for (int i = t; i < 800; i += 384) {
        const int k2 = i >> 4, du = i & 15;
        float4 a = *(const float4*)(Vg + (size_t)(2 * k2) * 64 + du * 4);
        float4 b = *(const float4*)(Vg + (size_t)(2 * k2 + 1) * 64 + du * 4);
        uint4 w;
        w.x = pkbf(a.x, b.x); w.y = pkbf(a.y, b.y);
        w.z = pkbf(a.z, b.z); w.w = pkbf(a.w, b.w);
        *(uint4*)(V_pk + k2 * 64 + du * 4) = w;
    }
    if (t < 128) bmws_s[t] = make_float2(bm[t], Ws[t]);
    const float bsv = bs_[0];
    __syncthreads();

    const int wv = t >> 6, lane = t & 63;
    const int lr = lane & 15, lq = lane >> 4;
    float* p_w = p_ws[wv];
    float* pool_w = pool_ws[wv];
    float* lg_w = lg_ws[wv];
    const int d = lane;
    const int b_ = bh >> 3, hh = bh & 7;
    const float bcd = bc[d];
    const float km6 = (lr < 4) ? 1.f : 0.f;

    for (int qi = wv; qi < nq; qi += 6) {
        const int q = q0 + qi;
        const size_t qb = ((size_t)bh * NQv + q) * 64;

        float q1v[2][8];
#pragma unroll
        for (int ks = 0; ks < 2; ks++) {
            float4 x = *(const float4*)(q1g + qb + ks * 32 + lq * 8);
            float4 y = *(const float4*)(q1g + qb + ks * 32 + lq * 8 + 4);
            q1v[ks][0] = x.x; q1v[ks][1] = x.y; q1v[ks][2] = x.z; q1v[ks][3] = x.w;
            q1v[ks][4] = y.x; q1v[ks][5] = y.y; q1v[ks][6] = y.z; q1v[ks][7] = y.w;
        }

        float pool_acc[8][4];
#pragma unroll
        for (int mt = 0; mt < 8; mt++)
#pragma unroll
            for (int r = 0; r < 4; r++) pool_acc[mt][r] = 0.f;

        // ---- kt loop: NOT unrolled (one bfr pair live at a time) ----
#pragma unroll 1
        for (int kt = 0; kt < 7; kt++) {
            const int k = kt * 16 + lr;
            const int kr = (k < 100) ? k : 99;
            const float km = (kt < 6) ? 1.f : km6;

            uint4 bfr0, bfr1;
#pragma unroll
            for (int ks = 0; ks < 2; ks++) {
                const int uu = ks * 4 + lq;
                uint4 Ka = *(const uint4*)((const char*)K_s + kr * 128 + ((uu ^ (kr & 7)) * 16));
                uint4 w;
#pragma unroll
                for (int j = 0; j < 4; j++) {
                    const unsigned int u0 = ((const unsigned int*)&Ka)[j];
                    const float klo = __uint_as_float(u0 << 16);
                    const float khi = __uint_as_float(u0 & 0xffff0000u);
                    ((unsigned int*)&w)[j] = pkbf(klo * q1v[ks][2 * j], khi * q1v[ks][2 * j + 1]);
                }
                if (ks == 0) bfr0 = w; else bfr1 = w;
            }

            float lgA = 0.f, lgB = 0.f;
#pragma unroll
            for (int mt = 0; mt < 8; mt++) {
                int m = mt * 16 + lr;
                asm volatile("" : "+v"(m));   // opaque: prevents hoisting afr/bmws reads
                const char* wrow = (const char*)Wm_s + m * 128;
                short8 afr0 = *(const short8*)(wrow + ((lq ^ (m & 7)) * 16));
                short8 afr1 = *(const short8*)(wrow + (((4 + lq) ^ (m & 7)) * 16));
                f32x4 acc = (f32x4){0.f, 0.f, 0.f, 0.f};
                acc = __builtin_amdgcn_mfma_f32_16x16x32_bf16(afr0, *(const short8*)&bfr0, acc, 0, 0, 0);
                acc = __builtin_amdgcn_mfma_f32_16x16x32_bf16(afr1, *(const short8*)&bfr1, acc, 0, 0, 0);
                const float2* bw = &bmws_s[(m - lr) + lq * 4];
                float4 bwa = *(const float4*)(bw);
                float4 bwb = *(const float4*)(bw + 2);
                const float v0 = fmaxf(acc[0] + bwa.x, 0.f);
                const float v1 = fmaxf(acc[1] + bwa.z, 0.f);
                const float v2 = fmaxf(acc[2] + bwb.x, 0.f);
                const float v3 = fmaxf(acc[3] + bwb.z, 0.f);
                lgA = fmaf(bwa.y, v0, lgA); lgA = fmaf(bwa.w, v1, lgA);
                lgB = fmaf(bwb.y, v2, lgB); lgB = fmaf(bwb.w, v3, lgB);
                pool_acc[mt][0] = fmaf(v0, km, pool_acc[mt][0]);
                pool_acc[mt][1] = fmaf(v1, km, pool_acc[mt][1]);
                pool_acc[mt][2] = fmaf(v2, km, pool_acc[mt][2]);
                pool_acc[mt][3] = fmaf(v3, km, pool_acc[mt][3]);
            }
            float lg = lgA + lgB;
            lg += __shfl_xor(lg, 16);
            lg += __shfl_xor(lg, 32);
            if (lq == 0) lg_w[kt * 16 + lr] = lg + bsv;
        }

        // ---- pool reduce over lr + write per-wave pool (x0.01) ----
#pragma unroll
        for (int mt = 0; mt < 8; mt++) {
#pragma unroll
            for (int r = 0; r < 4; r++) {
                pool_acc[mt][r] += __shfl_xor(pool_acc[mt][r], 1);
                pool_acc[mt][r] += __shfl_xor(pool_acc[mt][r], 2);
                pool_acc[mt][r] += __shfl_xor(pool_acc[mt][r], 4);
                pool_acc[mt][r] += __shfl_xor(pool_acc[mt][r], 8);
            }
            if (lr == 0)
                *(float4*)&pool_w[mt * 16 + lq * 4] = make_float4(
                    pool_acc[mt][0] * 0.01f, pool_acc[mt][1] * 0.01f,
                    pool_acc[mt][2] * 0.01f, pool_acc[mt][3] * 0.01f);
        }

        // ---- softmax over 100 k ----
        float lg[7];
#pragma unroll
        for (int kt = 0; kt < 7; kt++) lg[kt] = lg_w[kt * 16 + lr];
        float mx = -3.0e38f;
#pragma unroll
        for (int kt = 0; kt < 6; kt++) mx = fmaxf(mx, lg[kt]);
        if (lr < 4) mx = fmaxf(mx, lg[6]);
        mx = fmaxf(mx, __shfl_xor(mx, 1));
        mx = fmaxf(mx, __shfl_xor(mx, 2));
        mx = fmaxf(mx, __shfl_xor(mx, 4));
        mx = fmaxf(mx, __shfl_xor(mx, 8));
        float e[7];
        float sm = 0.f;
#pragma unroll
        for (int kt = 0; kt < 7; kt++) {
            const bool valid = (kt < 6) | (lr < 4);
            e[kt] = valid ? __expf(lg[kt] - mx) : 0.f;
            sm += e[kt];
        }
        sm += __shfl_xor(sm, 1);
        sm += __shfl_xor(sm, 2);
        sm += __shfl_xor(sm, 4);
        sm += __shfl_xor(sm, 8);
        const float inv = 1.f / sm;
        if (lq == 0) {
#pragma unroll
            for (int kt = 0; kt < 7; kt++) p_w[kt * 16 + lr] = e[kt] * inv;
        }

        // ---- sv (attn_spatial @ V) and ch (sigmoid channel), d = lane ----
        float sva = 0.f, svb = 0.f;
        for (int k2 = 0; k2 < 50; k2++) {
            const float2 pp = *(const float2*)&p_w[2 * k2];
            const unsigned int vp = V_pk[k2 * 64 + d];
            sva = fmaf(pp.x, __uint_as_float(vp << 16), sva);
            svb = fmaf(pp.y, __uint_as_float(vp & 0xffff0000u), svb);
        }
        float cha = 0.f, chb = 0.f;
        for (int m2 = 0; m2 < 64; m2++) {
            const float2 pl = *(const float2*)&pool_w[2 * m2];
            const unsigned int wp = wcp[m2 * 64 + d];
            cha = fmaf(pl.x, __uint_as_float(wp << 16), cha);
            chb = fmaf(pl.y, __uint_as_float(wp & 0xffff0000u), chb);
        }
        const float ch = 1.f / (1.f + __expf(-((cha + chb) + bcd)));
        const float ov = (sva + svb) * q2g[qb + d] * ch;
        attn_v[(((size_t)(b_ * NQv + q) * NH) + hh) * 64 + d] = bf16u(ov);
    }
}

// ---------------- Kernel C: MFMA output projection (bf16 A copy) ----------------
__global__ __launch_bounds__(256) void out_proj_kernel(
    const unsigned short* __restrict__ x, const unsigned short* __restrict__ WT,
    const float* __restrict__ bo, float* __restrict__ out)
{
    __shared__ char A_s[64 * 144];
    __shared__ char B_s[64 * 144];

    const int t = threadIdx.x;
    const int r0 = blockIdx.x * 64;
    const int ct = blockIdx.y;

    const int lane = t & 63, wave = t >> 6;
    const int wr = wave >> 1, wc = wave & 1;
    const int lr = lane & 15, lq = lane >> 4;
    const int srow = t >> 2, sc = t & 3;

    f32x4 acc[2][2];
#pragma unroll
    for (int i = 0; i < 2; i++)
#pragma unroll
        for (int j = 0; j < 2; j++) acc[i][j] = (f32x4){0.f, 0.f, 0.f, 0.f};

    const int arow = (r0 + srow < 800) ? (r0 + srow) : 799;

    for (int kk = 0; kk < 8; kk++) {
        const int k0 = kk * 64;
#pragma unroll
        for (int uu = 0; uu < 2; uu++) {
            const int u = sc * 2 + uu;
            uint4 w = *(const uint4*)(x + (size_t)arow * 512 + k0 + u * 8);
            *(uint4*)(A_s + srow * 144 + u * 16) = w;
        }
#pragma unroll
        for (int uu = 0; uu < 2; uu++) {
            const int u = sc * 2 + uu;
            uint4 w = *(const uint4*)(WT + (size_t)(ct * 64 + srow) * 512 + k0 + u * 8);
            *(uint4*)(B_s + srow * 144 + u * 16) = w;
        }
        __syncthreads();
#pragma unroll
        for (int ks = 0; ks < 2; ks++) {
            short8 a0 = *(const short8*)(A_s + (wr * 32 + lr) * 144 + (ks * 4 + lq) * 16);
            short8 a1 = *(const short8*)(A_s + (wr * 32 + 16 + lr) * 144 + (ks * 4 + lq) * 16);
            short8 b0 = *(const short8*)(B_s + (wc * 32 + lr) * 144 + (ks * 4 + lq) * 16);
            short8 b1 = *(const short8*)(B_s + (wc * 32 + 16 + lr) * 144 + (ks * 4 + lq) * 16);
            acc[0][0] = __builtin_amdgcn_mfma_f32_16x16x32_bf16(a0, b0, acc[0][0], 0, 0, 0);
            acc[0][1] = __builtin_amdgcn_mfma_f32_16x16x32_bf16(a0, b1, acc[0][1], 0, 0, 0);
            acc[1][0] = __builtin_amdgcn_mfma_f32_16x16x32_bf16(a1, b0, acc[1][0], 0, 0, 0);
            acc[1][1] = __builtin_amdgcn_mfma_f32_16x16x32_bf16(a1, b1, acc[1][1], 0, 0, 0);
        }
        __syncthreads();
    }

#pragma unroll
    for (int nt = 0; nt < 2; nt++) {
        const int j = ct * 64 + wc * 32 + nt * 16 + lr;
        const float bias = bo[j];
#pragma unroll
        for (int mt = 0; mt < 2; mt++) {
#pragma unroll
            for (int r = 0; r < 4; r++) {
                const int rowg = r0 + wr * 32 + mt * 16 + lq * 4 + r;
                if (rowg < 800) out[(size_t)rowg * 512 + j] = acc[mt][nt][r] + bias;
            }
        }
    }
}

extern "C" void kernel_launch(void* const* d_in, const int* in_sizes, int n_in,
                              void* d_out, int out_size, void* d_ws, size_t ws_size,
                              hipStream_t stream) {
    (void)in_sizes; (void)n_in; (void)out_size; (void)ws_size;
    const float* queries = (const float*)d_in[0];
    const float* keys    = (const float*)d_in[1];
    const float* values  = (const float*)d_in[2];
    const float* W_q1 = (const float*)d_in[3];
    const float* b_q1 = (const float*)d_in[4];
    const float* g_q1w = (const float*)d_in[5];
    const float* g_q1b = (const float*)d_in[6];
    const float* W_q2 = (const float*)d_in[7];
    const float* b_q2 = (const float*)d_in[8];
    const float* g_q2w = (const float*)d_in[9];
    const float* g_q2b = (const float*)d_in[10];
    const float* W_k = (const float*)d_in[11];
    const float* b_k = (const float*)d_in[12];
    const float* g_kw = (const float*)d_in[13];
    const float* g_kb = (const float*)d_in[14];
    const float* W_v = (const float*)d_in[15];
    const float* b_v = (const float*)d_in[16];
    const float* g_vw = (const float*)d_in[17];
    const float* g_vb = (const float*)d_in[18];
    const float* W_m = (const float*)d_in[19];
    const float* b_m = (const float*)d_in[20];
    const float* W_s = (const float*)d_in[21];
    const float* b_s = (const float*)d_in[22];
    const float* W_c = (const float*)d_in[23];
    const float* b_c = (const float*)d_in[24];
    const float* W_o = (const float*)d_in[25];
    const float* b_o = (const float*)d_in[26];

    float* ws = (float*)d_ws;
    const size_t PROJ = (size_t)BSv * NQv * 512;  // 409600 floats
    float* q1 = ws;
    float* q2 = q1 + PROJ;
    float* kk = q2 + PROJ;
    float* vv = kk + PROJ;
    unsigned short* av = (unsigned short*)(vv + PROJ);              // attn_v bf16 [800][512]
    unsigned short* wt = av + PROJ;                                  // 5 x [512][512] bf16
    unsigned int* wcp = (unsigned int*)(wt + (size_t)5 * 512 * 512); // [64][64] packed Wc
    unsigned short* xbf = (unsigned short*)(wcp + 4096);             // 3 x [800][512] bf16

    wt_kernel<<<dim3(8, 8, 9), 256, 0, stream>>>(
        W_q1, W_q2, W_k, W_v, W_o, W_c, queries, keys, values, wt, wcp, xbf);

    proj_kernel<<<dim3(13, 8, 4), 256, 0, stream>>>(
        xbf, wt,
        b_q1, g_q1w, g_q1b,
        b_q2, g_q2w, g_q2b,
        b_k, g_kw, g_kb,
        b_v, g_vw, g_vb,
        q1, q2, kk, vv);

    attn_kernel<<<dim3(8, BSv * NH), 384, 0, stream>>>(
        q1, q2, kk, vv, W_m, b_m, W_s, b_s, wcp, b_c, av);

    out_proj_kernel<<<dim3(13, 8), 256, 0, stream>>>(av, wt + (size_t)4 * 512 * 512, b_o, (float*)d_out);
}

// Round 17
// 87.028 us; speedup vs baseline: 1.3026x; 1.3026x over previous
//
#include <hip/hip_runtime.h>
#include <hip/hip_bf16.h>
#include <math.h>

#define NH 8
#define DMv 512
#define BSv 8
#define NQv 100
#define NKv 100

typedef __attribute__((ext_vector_type(8))) short short8;
typedef __attribute__((ext_vector_type(4))) float f32x4;

__device__ __forceinline__ unsigned short bf16u(float f) {
    __hip_bfloat16 h = __float2bfloat16(f);
    return *(unsigned short*)&h;
}
__device__ __forceinline__ unsigned int pkbf(float lo, float hi) {
    return ((unsigned int)bf16u(hi) << 16) | (unsigned int)bf16u(lo);
}

// -------- Kernel 0: weight transpose + bf16 convert (+ Wc pack z==5, X->bf16 z==6..8) --------
__global__ __launch_bounds__(256) void wt_kernel(
    const float* __restrict__ W_q1, const float* __restrict__ W_q2,
    const float* __restrict__ W_k,  const float* __restrict__ W_v,
    const float* __restrict__ W_o,  const float* __restrict__ Wc,
    const float* __restrict__ xq,   const float* __restrict__ xk, const float* __restrict__ xv,
    unsigned short* __restrict__ wt, unsigned int* __restrict__ wcp,
    unsigned short* __restrict__ xbf)
{
    __shared__ float tile[64][68];
    const int z = blockIdx.z;
    const int t = threadIdx.x;
    if (z == 5) {
        if (blockIdx.x != 0 || blockIdx.y != 0) return;
        for (int i = t; i < 4096; i += 256) {
            const int m2 = i >> 6, d = i & 63;
            wcp[i] = pkbf(Wc[(size_t)(2 * m2) * 64 + d], Wc[(size_t)(2 * m2 + 1) * 64 + d]);
        }
        return;
    }
    if (z >= 6) {
        const float* xs = (z == 6) ? xq : (z == 7) ? xk : xv;
        unsigned short* xo = xbf + (size_t)(z - 6) * 409600;
        const int bid = blockIdx.y * 8 + blockIdx.x;
        for (int i = bid * 256 + t; i < 51200; i += 64 * 256) {
            float4 a = *(const float4*)(xs + (size_t)i * 8);
            float4 b = *(const float4*)(xs + (size_t)i * 8 + 4);
            uint4 w;
            w.x = pkbf(a.x, a.y); w.y = pkbf(a.z, a.w);
            w.z = pkbf(b.x, b.y); w.w = pkbf(b.z, b.w);
            *(uint4*)(xo + (size_t)i * 8) = w;
        }
        return;
    }
    const float* W = (z == 0) ? W_q1 : (z == 1) ? W_q2 : (z == 2) ? W_k : (z == 3) ? W_v : W_o;
    unsigned short* out = wt + (size_t)z * 512 * 512;
    const int k0 = blockIdx.x * 64, n0 = blockIdx.y * 64;
    const int r = t >> 2, c = t & 3;
#pragma unroll
    for (int i = 0; i < 4; i++) {
        float4 v = *(const float4*)&W[(size_t)(k0 + r) * 512 + n0 + c * 16 + i * 4];
        *(float4*)&tile[r][c * 16 + i * 4] = v;
    }
    __syncthreads();
#pragma unroll
    for (int jj = 0; jj < 4; jj++) {
        const int kb = c * 16 + jj * 4;
        ushort4 u;
        u.x = bf16u(tile[kb + 0][r]); u.y = bf16u(tile[kb + 1][r]);
        u.z = bf16u(tile[kb + 2][r]); u.w = bf16u(tile[kb + 3][r]);
        *(ushort4*)&out[(size_t)(n0 + r) * 512 + k0 + kb] = u;
    }
}

// ---------------- Kernel A: MFMA proj GEMM + bias + ELU + GroupNorm (bf16 A copy) ----------------
__global__ __launch_bounds__(256) void proj_kernel(
    const unsigned short* __restrict__ xbf,
    const unsigned short* __restrict__ wt,
    const float* __restrict__ bq1, const float* __restrict__ gq1w, const float* __restrict__ gq1b,
    const float* __restrict__ bq2, const float* __restrict__ gq2w, const float* __restrict__ gq2b,
    const float* __restrict__ bk,  const float* __restrict__ gkw,  const float* __restrict__ gkb,
    const float* __restrict__ bv,  const float* __restrict__ gvw,  const float* __restrict__ gvb,
    float* __restrict__ q1o, float* __restrict__ q2o, float* __restrict__ ko, float* __restrict__ vo)
{
    __shared__ char A_s[64 * 144];
    __shared__ char B_s[64 * 144];
    __shared__ float Y_s[64][68];

    const int p = blockIdx.z;
    const unsigned short* x;
    const float *bb, *gw, *gb;
    float* o;
    if (p == 0)      { x = xbf;           bb = bq1; gw = gq1w; gb = gq1b; o = q1o; }
    else if (p == 1) { x = xbf;           bb = bq2; gw = gq2w; gb = gq2b; o = q2o; }
    else if (p == 2) { x = xbf + 409600;  bb = bk;  gw = gkw;  gb = gkb;  o = ko;  }
    else             { x = xbf + 819200;  bb = bv;  gw = gvw;  gb = gvb;  o = vo;  }
    const unsigned short* WT = wt + (size_t)p * 512 * 512;

    const int t = threadIdx.x;
    const int r0 = blockIdx.x * 64;
    const int ct = blockIdx.y;

    const int lane = t & 63, wave = t >> 6;
    const int wr = wave >> 1, wc = wave & 1;
    const int lr = lane & 15, lq = lane >> 4;
    const int srow = t >> 2, sc = t & 3;

    f32x4 acc[2][2];
#pragma unroll
    for (int i = 0; i < 2; i++)
#pragma unroll
        for (int j = 0; j < 2; j++) acc[i][j] = (f32x4){0.f, 0.f, 0.f, 0.f};

    const int arow = (r0 + srow < 800) ? (r0 + srow) : 799;

    for (int kk = 0; kk < 8; kk++) {
        const int k0 = kk * 64;
#pragma unroll
        for (int uu = 0; uu < 2; uu++) {
            const int u = sc * 2 + uu;
            uint4 w = *(const uint4*)(x + (size_t)arow * 512 + k0 + u * 8);
            *(uint4*)(A_s + srow * 144 + u * 16) = w;
        }
#pragma unroll
        for (int uu = 0; uu < 2; uu++) {
            const int u = sc * 2 + uu;
            uint4 w = *(const uint4*)(WT + (size_t)(ct * 64 + srow) * 512 + k0 + u * 8);
            *(uint4*)(B_s + srow * 144 + u * 16) = w;
        }
        __syncthreads();
#pragma unroll
        for (int ks = 0; ks < 2; ks++) {
            short8 a0 = *(const short8*)(A_s + (wr * 32 + lr) * 144 + (ks * 4 + lq) * 16);
            short8 a1 = *(const short8*)(A_s + (wr * 32 + 16 + lr) * 144 + (ks * 4 + lq) * 16);
            short8 b0 = *(const short8*)(B_s + (wc * 32 + lr) * 144 + (ks * 4 + lq) * 16);
            short8 b1 = *(const short8*)(B_s + (wc * 32 + 16 + lr) * 144 + (ks * 4 + lq) * 16);
            acc[0][0] = __builtin_amdgcn_mfma_f32_16x16x32_bf16(a0, b0, acc[0][0], 0, 0, 0);
            acc[0][1] = __builtin_amdgcn_mfma_f32_16x16x32_bf16(a0, b1, acc[0][1], 0, 0, 0);
            acc[1][0] = __builtin_amdgcn_mfma_f32_16x16x32_bf16(a1, b0, acc[1][0], 0, 0, 0);
            acc[1][1] = __builtin_amdgcn_mfma_f32_16x16x32_bf16(a1, b1, acc[1][1], 0, 0, 0);
        }
        __syncthreads();
    }

#pragma unroll
    for (int nt = 0; nt < 2; nt++) {
        const int colL = wc * 32 + nt * 16 + lr;
        const float bias = bb[ct * 64 + colL];
#pragma unroll
        for (int mt = 0; mt < 2; mt++) {
#pragma unroll
            for (int r = 0; r < 4; r++) {
                const int row = wr * 32 + mt * 16 + lq * 4 + r;
                float y = acc[mt][nt][r] + bias;
                y = (y > 0.f) ? y : expm1f(y);
                Y_s[row][colL] = y;
            }
        }
    }
    __syncthreads();

    {
        const int row = t >> 2, c = t & 3;
        float v[16];
        float s = 0.f, ss = 0.f;
#pragma unroll
        for (int i = 0; i < 16; i++) {
            v[i] = Y_s[row][c * 16 + i];
            s += v[i]; ss += v[i] * v[i];
        }
        s += __shfl_xor(s, 1); ss += __shfl_xor(ss, 1);
        s += __shfl_xor(s, 2); ss += __shfl_xor(ss, 2);
        const float mu = s * (1.f / 64.f);
        const float var = ss * (1.f / 64.f) - mu * mu;
        const float rs = 1.0f / sqrtf(var + 1e-5f);
        const int rowg = r0 + row;
        if (rowg < 800) {
            const int b = rowg / 100, sq = rowg % 100;
            const size_t base = (((size_t)(b * NH + ct) * NQv) + sq) * 64 + c * 16;
            const int j0 = ct * 64 + c * 16;
#pragma unroll
            for (int i4 = 0; i4 < 4; i4++) {
                float4 gwv = *(const float4*)&gw[j0 + i4 * 4];
                float4 gbv = *(const float4*)&gb[j0 + i4 * 4];
                float4 ov;
                ov.x = (v[i4 * 4 + 0] - mu) * rs * gwv.x + gbv.x;
                ov.y = (v[i4 * 4 + 1] - mu) * rs * gwv.y + gbv.y;
                ov.z = (v[i4 * 4 + 2] - mu) * rs * gwv.z + gbv.z;
                ov.w = (v[i4 * 4 + 3] - mu) * rs * gwv.w + gbv.w;
                *(float4*)&o[base + i4 * 4] = ov;
            }
        }
    }
}

// ---------------- Kernel B v10 (proven 61.4us): barrier-free, register-disciplined, bf16 out ----------------
__global__ __launch_bounds__(512) void attn_kernel(
    const float* __restrict__ q1g, const float* __restrict__ q2g,
    const float* __restrict__ kg, const float* __restrict__ vg,
    const float* __restrict__ Wm, const float* __restrict__ bm,
    const float* __restrict__ Ws, const float* __restrict__ bs_,
    const unsigned int* __restrict__ wcp, const float* __restrict__ bc,
    unsigned short* __restrict__ attn_v)
{
    __shared__ unsigned short Wm_s[8192];   // [128 m][64 d] bf16 swizzled
    __shared__ unsigned short K_s[6400];    // [100 k][64 d] bf16 swizzled
    __shared__ unsigned int  V_pk[3200];    // [50 k2][64 d] packed bf16 pair
    __shared__ float2 bmws_s[128];          // (b_m, W_s)
    __shared__ float p_ws[8][128];          // per-wave softmax probs
    __shared__ float pool_ws[8][128];       // per-wave pooled attn_map (x0.01)
    __shared__ float lg_ws[8][112];         // per-wave raw logits

    const int t = threadIdx.x;
    const int qt = blockIdx.x;     // 0..3
    const int bh = blockIdx.y;     // 0..63
    const int q0 = qt * 25;

    const float* Kg = kg + (size_t)bh * NKv * 64;
    const float* Vg = vg + (size_t)bh * NKv * 64;

    // ---- prologue staging (single barrier) ----
    for (int i = t; i < 800; i += 512) {
        const int k = i >> 3, u = i & 7;
        float4 a = *(const float4*)(Kg + k * 64 + u * 8);
        float4 b = *(const float4*)(Kg + k * 64 + u * 8 + 4);
        uint4 w;
        w.x = pkbf(a.x, a.y); w.y = pkbf(a.z, a.w);
        w.z = pkbf(b.x, b.y); w.w = pkbf(b.z, b.w);
        *(uint4*)((char*)K_s + k * 128 + ((u ^ (k & 7)) * 16)) = w;
    }
    for (int i = t; i < 1024; i += 512) {
        const int u = i >> 7, m = i & 127;
        float f[8];
#pragma unroll
        for (int j = 0; j < 8; j++) f[j] = Wm[(size_t)(u * 8 + j) * 128 + m];
        uint4 w;
        w.x = pkbf(f[0], f[1]); w.y = pkbf(f[2], f[3]);
        w.z = pkbf(f[4], f[5]); w.w = pkbf(f[6], f[7]);
        *(uint4*)((char*)Wm_s + m * 128 + ((u ^ (m & 7)) * 16)) = w;
    }
    for (int i = t; i < 800; i += 512) {
        const int k2 = i >> 4, du = i & 15;
        float4 a = *(const float4*)(Vg + (size_t)(2 * k2) * 64 + du * 4);
        float4 b = *(const float4*)(Vg + (size_t)(2 * k2 + 1) * 64 + du * 4);
        uint4 w;
        w.x = pkbf(a.x, b.x); w.y = pkbf(a.y, b.y);
        w.z = pkbf(a.z, b.z); w.w = pkbf(a.w, b.w);
        *(uint4*)(V_pk + k2 * 64 + du * 4) = w;
    }
    if (t < 128) bmws_s[t] = make_float2(bm[t], Ws[t]);
    const float bsv = bs_[0];
    __syncthreads();

    const int wv = t >> 6, lane = t & 63;
    const int lr = lane & 15, lq = lane >> 4;
    float* p_w = p_ws[wv];
    float* pool_w = pool_ws[wv];
    float* lg_w = lg_ws[wv];
    const int d = lane;
    const int b_ = bh >> 3, hh = bh & 7;
    const float bcd = bc[d];
    const float km6 = (lr < 4) ? 1.f : 0.f;

    for (int qi = wv; qi < 25; qi += 8) {
        const int q = q0 + qi;
        const size_t qb = ((size_t)bh * NQv + q) * 64;

        float q1v[2][8];
#pragma unroll
        for (int ks = 0; ks < 2; ks++) {
            float4 x = *(const float4*)(q1g + qb + ks * 32 + lq * 8);
            float4 y = *(const float4*)(q1g + qb + ks * 32 + lq * 8 + 4);
            q1v[ks][0] = x.x; q1v[ks][1] = x.y; q1v[ks][2] = x.z; q1v[ks][3] = x.w;
            q1v[ks][4] = y.x; q1v[ks][5] = y.y; q1v[ks][6] = y.z; q1v[ks][7] = y.w;
        }

        float pool_acc[8][4];
#pragma unroll
        for (int mt = 0; mt < 8; mt++)
#pragma unroll
            for (int r = 0; r < 4; r++) pool_acc[mt][r] = 0.f;

        // ---- kt loop: NOT unrolled (one bfr pair live at a time) ----
#pragma unroll 1
        for (int kt = 0; kt < 7; kt++) {
            const int k = kt * 16 + lr;
            const int kr = (k < 100) ? k : 99;
            const float km = (kt < 6) ? 1.f : km6;

            uint4 bfr0, bfr1;
#pragma unroll
            for (int ks = 0; ks < 2; ks++) {
                const int uu = ks * 4 + lq;
                uint4 Ka = *(const uint4*)((const char*)K_s + kr * 128 + ((uu ^ (kr & 7)) * 16));
                uint4 w;
#pragma unroll
                for (int j = 0; j < 4; j++) {
                    const unsigned int u0 = ((const unsigned int*)&Ka)[j];
                    const float klo = __uint_as_float(u0 << 16);
                    const float khi = __uint_as_float(u0 & 0xffff0000u);
                    ((unsigned int*)&w)[j] = pkbf(klo * q1v[ks][2 * j], khi * q1v[ks][2 * j + 1]);
                }
                if (ks == 0) bfr0 = w; else bfr1 = w;
            }

            float lgA = 0.f, lgB = 0.f;
#pragma unroll
            for (int mt = 0; mt < 8; mt++) {
                int m = mt * 16 + lr;
                asm volatile("" : "+v"(m));   // opaque: prevents hoisting afr/bmws reads
                const char* wrow = (const char*)Wm_s + m * 128;
                short8 afr0 = *(const short8*)(wrow + ((lq ^ (m & 7)) * 16));
                short8 afr1 = *(const short8*)(wrow + (((4 + lq) ^ (m & 7)) * 16));
                f32x4 acc = (f32x4){0.f, 0.f, 0.f, 0.f};
                acc = __builtin_amdgcn_mfma_f32_16x16x32_bf16(afr0, *(const short8*)&bfr0, acc, 0, 0, 0);
                acc = __builtin_amdgcn_mfma_f32_16x16x32_bf16(afr1, *(const short8*)&bfr1, acc, 0, 0, 0);
                const float2* bw = &bmws_s[(m - lr) + lq * 4];
                float4 bwa = *(const float4*)(bw);
                float4 bwb = *(const float4*)(bw + 2);
                const float v0 = fmaxf(acc[0] + bwa.x, 0.f);
                const float v1 = fmaxf(acc[1] + bwa.z, 0.f);
                const float v2 = fmaxf(acc[2] + bwb.x, 0.f);
                const float v3 = fmaxf(acc[3] + bwb.z, 0.f);
                lgA = fmaf(bwa.y, v0, lgA); lgA = fmaf(bwa.w, v1, lgA);
                lgB = fmaf(bwb.y, v2, lgB); lgB = fmaf(bwb.w, v3, lgB);
                pool_acc[mt][0] = fmaf(v0, km, pool_acc[mt][0]);
                pool_acc[mt][1] = fmaf(v1, km, pool_acc[mt][1]);
                pool_acc[mt][2] = fmaf(v2, km, pool_acc[mt][2]);
                pool_acc[mt][3] = fmaf(v3, km, pool_acc[mt][3]);
            }
            float lg = lgA + lgB;
            lg += __shfl_xor(lg, 16);
            lg += __shfl_xor(lg, 32);
            if (lq == 0) lg_w[kt * 16 + lr] = lg + bsv;
        }

        // ---- pool reduce over lr + write per-wave pool (x0.01) ----
#pragma unroll
        for (int mt = 0; mt < 8; mt++) {
#pragma unroll
            for (int r = 0; r < 4; r++) {
                pool_acc[mt][r] += __shfl_xor(pool_acc[mt][r], 1);
                pool_acc[mt][r] += __shfl_xor(pool_acc[mt][r], 2);
                pool_acc[mt][r] += __shfl_xor(pool_acc[mt][r], 4);
                pool_acc[mt][r] += __shfl_xor(pool_acc[mt][r], 8);
            }
            if (lr == 0)
                *(float4*)&pool_w[mt * 16 + lq * 4] = make_float4(
                    pool_acc[mt][0] * 0.01f, pool_acc[mt][1] * 0.01f,
                    pool_acc[mt][2] * 0.01f, pool_acc[mt][3] * 0.01f);
        }

        // ---- softmax over 100 k ----
        float lg[7];
#pragma unroll
        for (int kt = 0; kt < 7; kt++) lg[kt] = lg_w[kt * 16 + lr];
        float mx = -3.0e38f;
#pragma unroll
        for (int kt = 0; kt < 6; kt++) mx = fmaxf(mx, lg[kt]);
        if (lr < 4) mx = fmaxf(mx, lg[6]);
        mx = fmaxf(mx, __shfl_xor(mx, 1));
        mx = fmaxf(mx, __shfl_xor(mx, 2));
        mx = fmaxf(mx, __shfl_xor(mx, 4));
        mx = fmaxf(mx, __shfl_xor(mx, 8));
        float e[7];
        float sm = 0.f;
#pragma unroll
        for (int kt = 0; kt < 7; kt++) {
            const bool valid = (kt < 6) | (lr < 4);
            e[kt] = valid ? __expf(lg[kt] - mx) : 0.f;
            sm += e[kt];
        }
        sm += __shfl_xor(sm, 1);
        sm += __shfl_xor(sm, 2);
        sm += __shfl_xor(sm, 4);
        sm += __shfl_xor(sm, 8);
        const float inv = 1.f / sm;
        if (lq == 0) {
#pragma unroll
            for (int kt = 0; kt < 7; kt++) p_w[kt * 16 + lr] = e[kt] * inv;
        }

        // ---- sv (attn_spatial @ V) and ch (sigmoid channel), d = lane ----
        float sva = 0.f, svb = 0.f;
        for (int k2 = 0; k2 < 50; k2++) {
            const float2 pp = *(const float2*)&p_w[2 * k2];
            const unsigned int vp = V_pk[k2 * 64 + d];
            sva = fmaf(pp.x, __uint_as_float(vp << 16), sva);
            svb = fmaf(pp.y, __uint_as_float(vp & 0xffff0000u), svb);
        }
        float cha = 0.f, chb = 0.f;
        for (int m2 = 0; m2 < 64; m2++) {
            const float2 pl = *(const float2*)&pool_w[2 * m2];
            const unsigned int wp = wcp[m2 * 64 + d];
            cha = fmaf(pl.x, __uint_as_float(wp << 16), cha);
            chb = fmaf(pl.y, __uint_as_float(wp & 0xffff0000u), chb);
        }
        const float ch = 1.f / (1.f + __expf(-((cha + chb) + bcd)));
        const float ov = (sva + svb) * q2g[qb + d] * ch;
        attn_v[(((size_t)(b_ * NQv + q) * NH) + hh) * 64 + d] = bf16u(ov);
    }
}

// ---------------- Kernel C: MFMA output projection (bf16 A copy) ----------------
__global__ __launch_bounds__(256) void out_proj_kernel(
    const unsigned short* __restrict__ x, const unsigned short* __restrict__ WT,
    const float* __restrict__ bo, float* __restrict__ out)
{
    __shared__ char A_s[64 * 144];
    __shared__ char B_s[64 * 144];

    const int t = threadIdx.x;
    const int r0 = blockIdx.x * 64;
    const int ct = blockIdx.y;

    const int lane = t & 63, wave = t >> 6;
    const int wr = wave >> 1, wc = wave & 1;
    const int lr = lane & 15, lq = lane >> 4;
    const int srow = t >> 2, sc = t & 3;

    f32x4 acc[2][2];
#pragma unroll
    for (int i = 0; i < 2; i++)
#pragma unroll
        for (int j = 0; j < 2; j++) acc[i][j] = (f32x4){0.f, 0.f, 0.f, 0.f};

    const int arow = (r0 + srow < 800) ? (r0 + srow) : 799;

    for (int kk = 0; kk < 8; kk++) {
        const int k0 = kk * 64;
#pragma unroll
        for (int uu = 0; uu < 2; uu++) {
            const int u = sc * 2 + uu;
            uint4 w = *(const uint4*)(x + (size_t)arow * 512 + k0 + u * 8);
            *(uint4*)(A_s + srow * 144 + u * 16) = w;
        }
#pragma unroll
        for (int uu = 0; uu < 2; uu++) {
            const int u = sc * 2 + uu;
            uint4 w = *(const uint4*)(WT + (size_t)(ct * 64 + srow) * 512 + k0 + u * 8);
            *(uint4*)(B_s + srow * 144 + u * 16) = w;
        }
        __syncthreads();
#pragma unroll
        for (int ks = 0; ks < 2; ks++) {
            short8 a0 = *(const short8*)(A_s + (wr * 32 + lr) * 144 + (ks * 4 + lq) * 16);
            short8 a1 = *(const short8*)(A_s + (wr * 32 + 16 + lr) * 144 + (ks * 4 + lq) * 16);
            short8 b0 = *(const short8*)(B_s + (wc * 32 + lr) * 144 + (ks * 4 + lq) * 16);
            short8 b1 = *(const short8*)(B_s + (wc * 32 + 16 + lr) * 144 + (ks * 4 + lq) * 16);
            acc[0][0] = __builtin_amdgcn_mfma_f32_16x16x32_bf16(a0, b0, acc[0][0], 0, 0, 0);
            acc[0][1] = __builtin_amdgcn_mfma_f32_16x16x32_bf16(a0, b1, acc[0][1], 0, 0, 0);
            acc[1][0] = __builtin_amdgcn_mfma_f32_16x16x32_bf16(a1, b0, acc[1][0], 0, 0, 0);
            acc[1][1] = __builtin_amdgcn_mfma_f32_16x16x32_bf16(a1, b1, acc[1][1], 0, 0, 0);
        }
        __syncthreads();
    }

#pragma unroll
    for (int nt = 0; nt < 2; nt++) {
        const int j = ct * 64 + wc * 32 + nt * 16 + lr;
        const float bias = bo[j];
#pragma unroll
        for (int mt = 0; mt < 2; mt++) {
#pragma unroll
            for (int r = 0; r < 4; r++) {
                const int rowg = r0 + wr * 32 + mt * 16 + lq * 4 + r;
                if (rowg < 800) out[(size_t)rowg * 512 + j] = acc[mt][nt][r] + bias;
            }
        }
    }
}

extern "C" void kernel_launch(void* const* d_in, const int* in_sizes, int n_in,
                              void* d_out, int out_size, void* d_ws, size_t ws_size,
                              hipStream_t stream) {
    (void)in_sizes; (void)n_in; (void)out_size; (void)ws_size;
    const float* queries = (const float*)d_in[0];
    const float* keys    = (const float*)d_in[1];
    const float* values  = (const float*)d_in[2];
    const float* W_q1 = (const float*)d_in[3];
    const float* b_q1 = (const float*)d_in[4];
    const float* g_q1w = (const float*)d_in[5];
    const float* g_q1b = (const float*)d_in[6];
    const float* W_q2 = (const float*)d_in[7];
    const float* b_q2 = (const float*)d_in[8];
    const float* g_q2w = (const float*)d_in[9];
    const float* g_q2b = (const float*)d_in[10];
    const float* W_k = (const float*)d_in[11];
    const float* b_k = (const float*)d_in[12];
    const float* g_kw = (const float*)d_in[13];
    const float* g_kb = (const float*)d_in[14];
    const float* W_v = (const float*)d_in[15];
    const float* b_v = (const float*)d_in[16];
    const float* g_vw = (const float*)d_in[17];
    const float* g_vb = (const float*)d_in[18];
    const float* W_m = (const float*)d_in[19];
    const float* b_m = (const float*)d_in[20];
    const float* W_s = (const float*)d_in[21];
    const float* b_s = (const float*)d_in[22];
    const float* W_c = (const float*)d_in[23];
    const float* b_c = (const float*)d_in[24];
    const float* W_o = (const float*)d_in[25];
    const float* b_o = (const float*)d_in[26];

    float* ws = (float*)d_ws;
    const size_t PROJ = (size_t)BSv * NQv * 512;  // 409600 floats
    float* q1 = ws;
    float* q2 = q1 + PROJ;
    float* kk = q2 + PROJ;
    float* vv = kk + PROJ;
    unsigned short* av = (unsigned short*)(vv + PROJ);              // attn_v bf16 [800][512]
    unsigned short* wt = av + PROJ;                                  // 5 x [512][512] bf16
    unsigned int* wcp = (unsigned int*)(wt + (size_t)5 * 512 * 512); // [64][64] packed Wc
    unsigned short* xbf = (unsigned short*)(wcp + 4096);             // 3 x [800][512] bf16

    wt_kernel<<<dim3(8, 8, 9), 256, 0, stream>>>(
        W_q1, W_q2, W_k, W_v, W_o, W_c, queries, keys, values, wt, wcp, xbf);

    proj_kernel<<<dim3(13, 8, 4), 256, 0, stream>>>(
        xbf, wt,
        b_q1, g_q1w, g_q1b,
        b_q2, g_q2w, g_q2b,
        b_k, g_kw, g_kb,
        b_v, g_vw, g_vb,
        q1, q2, kk, vv);

    attn_kernel<<<dim3(4, BSv * NH), 512, 0, stream>>>(
        q1, q2, kk, vv, W_m, b_m, W_s, b_s, wcp, b_c, av);

    out_proj_kernel<<<dim3(13, 8), 256, 0, stream>>>(av, wt + (size_t)4 * 512 * 512, b_o, (float*)d_out);
}

// Round 18
// 85.235 us; speedup vs baseline: 1.3300x; 1.0210x over previous
//
#include <hip/hip_runtime.h>
#include <hip/hip_bf16.h>
#include <math.h>

#define NH 8
#define DMv 512
#define BSv 8
#define NQv 100
#define NKv 100

typedef __attribute__((ext_vector_type(8))) short short8;
typedef __attribute__((ext_vector_type(4))) float f32x4;

__device__ __forceinline__ unsigned short bf16u(float f) {
    __hip_bfloat16 h = __float2bfloat16(f);
    return *(unsigned short*)&h;
}
__device__ __forceinline__ unsigned int pkbf(float lo, float hi) {
    return ((unsigned int)bf16u(hi) << 16) | (unsigned int)bf16u(lo);
}

// -------- Kernel 0: weight transpose + bf16 convert (+ Wc pack z==5, X->bf16 z==6..8) --------
__global__ __launch_bounds__(256) void wt_kernel(
    const float* __restrict__ W_q1, const float* __restrict__ W_q2,
    const float* __restrict__ W_k,  const float* __restrict__ W_v,
    const float* __restrict__ W_o,  const float* __restrict__ Wc,
    const float* __restrict__ xq,   const float* __restrict__ xk, const float* __restrict__ xv,
    unsigned short* __restrict__ wt, unsigned int* __restrict__ wcp,
    unsigned short* __restrict__ xbf)
{
    __shared__ float tile[64][68];
    const int z = blockIdx.z;
    const int t = threadIdx.x;
    if (z == 5) {
        if (blockIdx.x != 0 || blockIdx.y != 0) return;
        for (int i = t; i < 4096; i += 256) {
            const int m2 = i >> 6, d = i & 63;
            wcp[i] = pkbf(Wc[(size_t)(2 * m2) * 64 + d], Wc[(size_t)(2 * m2 + 1) * 64 + d]);
        }
        return;
    }
    if (z >= 6) {
        const float* xs = (z == 6) ? xq : (z == 7) ? xk : xv;
        unsigned short* xo = xbf + (size_t)(z - 6) * 409600;
        const int bid = blockIdx.y * 8 + blockIdx.x;
        for (int i = bid * 256 + t; i < 51200; i += 64 * 256) {
            float4 a = *(const float4*)(xs + (size_t)i * 8);
            float4 b = *(const float4*)(xs + (size_t)i * 8 + 4);
            uint4 w;
            w.x = pkbf(a.x, a.y); w.y = pkbf(a.z, a.w);
            w.z = pkbf(b.x, b.y); w.w = pkbf(b.z, b.w);
            *(uint4*)(xo + (size_t)i * 8) = w;
        }
        return;
    }
    const float* W = (z == 0) ? W_q1 : (z == 1) ? W_q2 : (z == 2) ? W_k : (z == 3) ? W_v : W_o;
    unsigned short* out = wt + (size_t)z * 512 * 512;
    const int k0 = blockIdx.x * 64, n0 = blockIdx.y * 64;
    const int r = t >> 2, c = t & 3;
#pragma unroll
    for (int i = 0; i < 4; i++) {
        float4 v = *(const float4*)&W[(size_t)(k0 + r) * 512 + n0 + c * 16 + i * 4];
        *(float4*)&tile[r][c * 16 + i * 4] = v;
    }
    __syncthreads();
#pragma unroll
    for (int jj = 0; jj < 4; jj++) {
        const int kb = c * 16 + jj * 4;
        ushort4 u;
        u.x = bf16u(tile[kb + 0][r]); u.y = bf16u(tile[kb + 1][r]);
        u.z = bf16u(tile[kb + 2][r]); u.w = bf16u(tile[kb + 3][r]);
        *(ushort4*)&out[(size_t)(n0 + r) * 512 + k0 + kb] = u;
    }
}

// ---------------- Kernel A: MFMA proj GEMM + bias + ELU + GroupNorm (bf16 A copy) ----------------
__global__ __launch_bounds__(256) void proj_kernel(
    const unsigned short* __restrict__ xbf,
    const unsigned short* __restrict__ wt,
    const float* __restrict__ bq1, const float* __restrict__ gq1w, const float* __restrict__ gq1b,
    const float* __restrict__ bq2, const float* __restrict__ gq2w, const float* __restrict__ gq2b,
    const float* __restrict__ bk,  const float* __restrict__ gkw,  const float* __restrict__ gkb,
    const float* __restrict__ bv,  const float* __restrict__ gvw,  const float* __restrict__ gvb,
    float* __restrict__ q1o, float* __restrict__ q2o, float* __restrict__ ko, float* __restrict__ vo)
{
    __shared__ char A_s[64 * 144];
    __shared__ char B_s[64 * 144];
    __shared__ float Y_s[64][68];

    const int p = blockIdx.z;
    const unsigned short* x;
    const float *bb, *gw, *gb;
    float* o;
    if (p == 0)      { x = xbf;           bb = bq1; gw = gq1w; gb = gq1b; o = q1o; }
    else if (p == 1) { x = xbf;           bb = bq2; gw = gq2w; gb = gq2b; o = q2o; }
    else if (p == 2) { x = xbf + 409600;  bb = bk;  gw = gkw;  gb = gkb;  o = ko;  }
    else             { x = xbf + 819200;  bb = bv;  gw = gvw;  gb = gvb;  o = vo;  }
    const unsigned short* WT = wt + (size_t)p * 512 * 512;

    const int t = threadIdx.x;
    const int r0 = blockIdx.x * 64;
    const int ct = blockIdx.y;

    const int lane = t & 63, wave = t >> 6;
    const int wr = wave >> 1, wc = wave & 1;
    const int lr = lane & 15, lq = lane >> 4;
    const int srow = t >> 2, sc = t & 3;

    f32x4 acc[2][2];
#pragma unroll
    for (int i = 0; i < 2; i++)
#pragma unroll
        for (int j = 0; j < 2; j++) acc[i][j] = (f32x4){0.f, 0.f, 0.f, 0.f};

    const int arow = (r0 + srow < 800) ? (r0 + srow) : 799;

    for (int kk = 0; kk < 8; kk++) {
        const int k0 = kk * 64;
#pragma unroll
        for (int uu = 0; uu < 2; uu++) {
            const int u = sc * 2 + uu;
            uint4 w = *(const uint4*)(x + (size_t)arow * 512 + k0 + u * 8);
            *(uint4*)(A_s + srow * 144 + u * 16) = w;
        }
#pragma unroll
        for (int uu = 0; uu < 2; uu++) {
            const int u = sc * 2 + uu;
            uint4 w = *(const uint4*)(WT + (size_t)(ct * 64 + srow) * 512 + k0 + u * 8);
            *(uint4*)(B_s + srow * 144 + u * 16) = w;
        }
        __syncthreads();
#pragma unroll
        for (int ks = 0; ks < 2; ks++) {
            short8 a0 = *(const short8*)(A_s + (wr * 32 + lr) * 144 + (ks * 4 + lq) * 16);
            short8 a1 = *(const short8*)(A_s + (wr * 32 + 16 + lr) * 144 + (ks * 4 + lq) * 16);
            short8 b0 = *(const short8*)(B_s + (wc * 32 + lr) * 144 + (ks * 4 + lq) * 16);
            short8 b1 = *(const short8*)(B_s + (wc * 32 + 16 + lr) * 144 + (ks * 4 + lq) * 16);
            acc[0][0] = __builtin_amdgcn_mfma_f32_16x16x32_bf16(a0, b0, acc[0][0], 0, 0, 0);
            acc[0][1] = __builtin_amdgcn_mfma_f32_16x16x32_bf16(a0, b1, acc[0][1], 0, 0, 0);
            acc[1][0] = __builtin_amdgcn_mfma_f32_16x16x32_bf16(a1, b0, acc[1][0], 0, 0, 0);
            acc[1][1] = __builtin_amdgcn_mfma_f32_16x16x32_bf16(a1, b1, acc[1][1], 0, 0, 0);
        }
        __syncthreads();
    }

#pragma unroll
    for (int nt = 0; nt < 2; nt++) {
        const int colL = wc * 32 + nt * 16 + lr;
        const float bias = bb[ct * 64 + colL];
#pragma unroll
        for (int mt = 0; mt < 2; mt++) {
#pragma unroll
            for (int r = 0; r < 4; r++) {
                const int row = wr * 32 + mt * 16 + lq * 4 + r;
                float y = acc[mt][nt][r] + bias;
                y = (y > 0.f) ? y : expm1f(y);
                Y_s[row][colL] = y;
            }
        }
    }
    __syncthreads();

    {
        const int row = t >> 2, c = t & 3;
        float v[16];
        float s = 0.f, ss = 0.f;
#pragma unroll
        for (int i = 0; i < 16; i++) {
            v[i] = Y_s[row][c * 16 + i];
            s += v[i]; ss += v[i] * v[i];
        }
        s += __shfl_xor(s, 1); ss += __shfl_xor(ss, 1);
        s += __shfl_xor(s, 2); ss += __shfl_xor(ss, 2);
        const float mu = s * (1.f / 64.f);
        const float var = ss * (1.f / 64.f) - mu * mu;
        const float rs = 1.0f / sqrtf(var + 1e-5f);
        const int rowg = r0 + row;
        if (rowg < 800) {
            const int b = rowg / 100, sq = rowg % 100;
            const size_t base = (((size_t)(b * NH + ct) * NQv) + sq) * 64 + c * 16;
            const int j0 = ct * 64 + c * 16;
#pragma unroll
            for (int i4 = 0; i4 < 4; i4++) {
                float4 gwv = *(const float4*)&gw[j0 + i4 * 4];
                float4 gbv = *(const float4*)&gb[j0 + i4 * 4];
                float4 ov;
                ov.x = (v[i4 * 4 + 0] - mu) * rs * gwv.x + gbv.x;
                ov.y = (v[i4 * 4 + 1] - mu) * rs * gwv.y + gbv.y;
                ov.z = (v[i4 * 4 + 2] - mu) * rs * gwv.z + gbv.z;
                ov.w = (v[i4 * 4 + 3] - mu) * rs * gwv.w + gbv.w;
                *(float4*)&o[base + i4 * 4] = ov;
            }
        }
    }
}

// ---------------- Kernel B v17: v10 + Ka prefetch pipeline (+8 transient regs) ----------------
// Hides the per-kt ds_read Ka latency (~120cyc) under the previous kt's mt loop.
// Only change vs the proven 61.4us kernel: KaN0/KaN1 double-buffer. Spill signature = FETCH balloon.
__global__ __launch_bounds__(512) void attn_kernel(
    const float* __restrict__ q1g, const float* __restrict__ q2g,
    const float* __restrict__ kg, const float* __restrict__ vg,
    const float* __restrict__ Wm, const float* __restrict__ bm,
    const float* __restrict__ Ws, const float* __restrict__ bs_,
    const unsigned int* __restrict__ wcp, const float* __restrict__ bc,
    unsigned short* __restrict__ attn_v)
{
    __shared__ unsigned short Wm_s[8192];   // [128 m][64 d] bf16 swizzled
    __shared__ unsigned short K_s[6400];    // [100 k][64 d] bf16 swizzled
    __shared__ unsigned int  V_pk[3200];    // [50 k2][64 d] packed bf16 pair
    __shared__ float2 bmws_s[128];          // (b_m, W_s)
    __shared__ float p_ws[8][128];          // per-wave softmax probs
    __shared__ float pool_ws[8][128];       // per-wave pooled attn_map (x0.01)
    __shared__ float lg_ws[8][112];         // per-wave raw logits

    const int t = threadIdx.x;
    const int qt = blockIdx.x;     // 0..3
    const int bh = blockIdx.y;     // 0..63
    const int q0 = qt * 25;

    const float* Kg = kg + (size_t)bh * NKv * 64;
    const float* Vg = vg + (size_t)bh * NKv * 64;

    // ---- prologue staging (single barrier) ----
    for (int i = t; i < 800; i += 512) {
        const int k = i >> 3, u = i & 7;
        float4 a = *(const float4*)(Kg + k * 64 + u * 8);
        float4 b = *(const float4*)(Kg + k * 64 + u * 8 + 4);
        uint4 w;
        w.x = pkbf(a.x, a.y); w.y = pkbf(a.z, a.w);
        w.z = pkbf(b.x, b.y); w.w = pkbf(b.z, b.w);
        *(uint4*)((char*)K_s + k * 128 + ((u ^ (k & 7)) * 16)) = w;
    }
    for (int i = t; i < 1024; i += 512) {
        const int u = i >> 7, m = i & 127;
        float f[8];
#pragma unroll
        for (int j = 0; j < 8; j++) f[j] = Wm[(size_t)(u * 8 + j) * 128 + m];
        uint4 w;
        w.x = pkbf(f[0], f[1]); w.y = pkbf(f[2], f[3]);
        w.z = pkbf(f[4], f[5]); w.w = pkbf(f[6], f[7]);
        *(uint4*)((char*)Wm_s + m * 128 + ((u ^ (m & 7)) * 16)) = w;
    }
    for (int i = t; i < 800; i += 512) {
        const int k2 = i >> 4, du = i & 15;
        float4 a = *(const float4*)(Vg + (size_t)(2 * k2) * 64 + du * 4);
        float4 b = *(const float4*)(Vg + (size_t)(2 * k2 + 1) * 64 + du * 4);
        uint4 w;
        w.x = pkbf(a.x, b.x); w.y = pkbf(a.y, b.y);
        w.z = pkbf(a.z, b.z); w.w = pkbf(a.w, b.w);
        *(uint4*)(V_pk + k2 * 64 + du * 4) = w;
    }
    if (t < 128) bmws_s[t] = make_float2(bm[t], Ws[t]);
    const float bsv = bs_[0];
    __syncthreads();

    const int wv = t >> 6, lane = t & 63;
    const int lr = lane & 15, lq = lane >> 4;
    float* p_w = p_ws[wv];
    float* pool_w = pool_ws[wv];
    float* lg_w = lg_ws[wv];
    const int d = lane;
    const int b_ = bh >> 3, hh = bh & 7;
    const float bcd = bc[d];
    const float km6 = (lr < 4) ? 1.f : 0.f;

    for (int qi = wv; qi < 25; qi += 8) {
        const int q = q0 + qi;
        const size_t qb = ((size_t)bh * NQv + q) * 64;

        float q1v[2][8];
#pragma unroll
        for (int ks = 0; ks < 2; ks++) {
            float4 x = *(const float4*)(q1g + qb + ks * 32 + lq * 8);
            float4 y = *(const float4*)(q1g + qb + ks * 32 + lq * 8 + 4);
            q1v[ks][0] = x.x; q1v[ks][1] = x.y; q1v[ks][2] = x.z; q1v[ks][3] = x.w;
            q1v[ks][4] = y.x; q1v[ks][5] = y.y; q1v[ks][6] = y.z; q1v[ks][7] = y.w;
        }

        float pool_acc[8][4];
#pragma unroll
        for (int mt = 0; mt < 8; mt++)
#pragma unroll
            for (int r = 0; r < 4; r++) pool_acc[mt][r] = 0.f;

        // ---- Ka prefetch for kt=0 (k = lr < 100 always) ----
        uint4 KaN0 = *(const uint4*)((const char*)K_s + lr * 128 + ((lq ^ (lr & 7)) * 16));
        uint4 KaN1 = *(const uint4*)((const char*)K_s + lr * 128 + (((4 + lq) ^ (lr & 7)) * 16));

        // ---- kt loop: NOT unrolled; Ka double-buffered ----
#pragma unroll 1
        for (int kt = 0; kt < 7; kt++) {
            const float km = (kt < 6) ? 1.f : km6;
            uint4 Ka0 = KaN0, Ka1 = KaN1;
            if (kt < 6) {
                const int kn = (kt + 1) * 16 + lr;
                const int krn = (kn < 100) ? kn : 99;
                KaN0 = *(const uint4*)((const char*)K_s + krn * 128 + ((lq ^ (krn & 7)) * 16));
                KaN1 = *(const uint4*)((const char*)K_s + krn * 128 + (((4 + lq) ^ (krn & 7)) * 16));
            }

            uint4 bfr0, bfr1;
#pragma unroll
            for (int j = 0; j < 4; j++) {
                const unsigned int u0 = ((const unsigned int*)&Ka0)[j];
                const float klo = __uint_as_float(u0 << 16);
                const float khi = __uint_as_float(u0 & 0xffff0000u);
                ((unsigned int*)&bfr0)[j] = pkbf(klo * q1v[0][2 * j], khi * q1v[0][2 * j + 1]);
                const unsigned int u1 = ((const unsigned int*)&Ka1)[j];
                const float klo1 = __uint_as_float(u1 << 16);
                const float khi1 = __uint_as_float(u1 & 0xffff0000u);
                ((unsigned int*)&bfr1)[j] = pkbf(klo1 * q1v[1][2 * j], khi1 * q1v[1][2 * j + 1]);
            }

            float lgA = 0.f, lgB = 0.f;
#pragma unroll
            for (int mt = 0; mt < 8; mt++) {
                int m = mt * 16 + lr;
                asm volatile("" : "+v"(m));   // opaque: prevents hoisting afr/bmws reads
                const char* wrow = (const char*)Wm_s + m * 128;
                short8 afr0 = *(const short8*)(wrow + ((lq ^ (m & 7)) * 16));
                short8 afr1 = *(const short8*)(wrow + (((4 + lq) ^ (m & 7)) * 16));
                f32x4 acc = (f32x4){0.f, 0.f, 0.f, 0.f};
                acc = __builtin_amdgcn_mfma_f32_16x16x32_bf16(afr0, *(const short8*)&bfr0, acc, 0, 0, 0);
                acc = __builtin_amdgcn_mfma_f32_16x16x32_bf16(afr1, *(const short8*)&bfr1, acc, 0, 0, 0);
                const float2* bw = &bmws_s[(m - lr) + lq * 4];
                float4 bwa = *(const float4*)(bw);
                float4 bwb = *(const float4*)(bw + 2);
                const float v0 = fmaxf(acc[0] + bwa.x, 0.f);
                const float v1 = fmaxf(acc[1] + bwa.z, 0.f);
                const float v2 = fmaxf(acc[2] + bwb.x, 0.f);
                const float v3 = fmaxf(acc[3] + bwb.z, 0.f);
                lgA = fmaf(bwa.y, v0, lgA); lgA = fmaf(bwa.w, v1, lgA);
                lgB = fmaf(bwb.y, v2, lgB); lgB = fmaf(bwb.w, v3, lgB);
                pool_acc[mt][0] = fmaf(v0, km, pool_acc[mt][0]);
                pool_acc[mt][1] = fmaf(v1, km, pool_acc[mt][1]);
                pool_acc[mt][2] = fmaf(v2, km, pool_acc[mt][2]);
                pool_acc[mt][3] = fmaf(v3, km, pool_acc[mt][3]);
            }
            float lg = lgA + lgB;
            lg += __shfl_xor(lg, 16);
            lg += __shfl_xor(lg, 32);
            if (lq == 0) lg_w[kt * 16 + lr] = lg + bsv;
        }

        // ---- pool reduce over lr + write per-wave pool (x0.01) ----
#pragma unroll
        for (int mt = 0; mt < 8; mt++) {
#pragma unroll
            for (int r = 0; r < 4; r++) {
                pool_acc[mt][r] += __shfl_xor(pool_acc[mt][r], 1);
                pool_acc[mt][r] += __shfl_xor(pool_acc[mt][r], 2);
                pool_acc[mt][r] += __shfl_xor(pool_acc[mt][r], 4);
                pool_acc[mt][r] += __shfl_xor(pool_acc[mt][r], 8);
            }
            if (lr == 0)
                *(float4*)&pool_w[mt * 16 + lq * 4] = make_float4(
                    pool_acc[mt][0] * 0.01f, pool_acc[mt][1] * 0.01f,
                    pool_acc[mt][2] * 0.01f, pool_acc[mt][3] * 0.01f);
        }

        // ---- softmax over 100 k ----
        float lg[7];
#pragma unroll
        for (int kt = 0; kt < 7; kt++) lg[kt] = lg_w[kt * 16 + lr];
        float mx = -3.0e38f;
#pragma unroll
        for (int kt = 0; kt < 6; kt++) mx = fmaxf(mx, lg[kt]);
        if (lr < 4) mx = fmaxf(mx, lg[6]);
        mx = fmaxf(mx, __shfl_xor(mx, 1));
        mx = fmaxf(mx, __shfl_xor(mx, 2));
        mx = fmaxf(mx, __shfl_xor(mx, 4));
        mx = fmaxf(mx, __shfl_xor(mx, 8));
        float e[7];
        float sm = 0.f;
#pragma unroll
        for (int kt = 0; kt < 7; kt++) {
            const bool valid = (kt < 6) | (lr < 4);
            e[kt] = valid ? __expf(lg[kt] - mx) : 0.f;
            sm += e[kt];
        }
        sm += __shfl_xor(sm, 1);
        sm += __shfl_xor(sm, 2);
        sm += __shfl_xor(sm, 4);
        sm += __shfl_xor(sm, 8);
        const float inv = 1.f / sm;
        if (lq == 0) {
#pragma unroll
            for (int kt = 0; kt < 7; kt++) p_w[kt * 16 + lr] = e[kt] * inv;
        }

        // ---- sv (attn_spatial @ V) and ch (sigmoid channel), d = lane ----
        float sva = 0.f, svb = 0.f;
        for (int k2 = 0; k2 < 50; k2++) {
            const float2 pp = *(const float2*)&p_w[2 * k2];
            const unsigned int vp = V_pk[k2 * 64 + d];
            sva = fmaf(pp.x, __uint_as_float(vp << 16), sva);
            svb = fmaf(pp.y, __uint_as_float(vp & 0xffff0000u), svb);
        }
        float cha = 0.f, chb = 0.f;
        for (int m2 = 0; m2 < 64; m2++) {
            const float2 pl = *(const float2*)&pool_w[2 * m2];
            const unsigned int wp = wcp[m2 * 64 + d];
            cha = fmaf(pl.x, __uint_as_float(wp << 16), cha);
            chb = fmaf(pl.y, __uint_as_float(wp & 0xffff0000u), chb);
        }
        const float ch = 1.f / (1.f + __expf(-((cha + chb) + bcd)));
        const float ov = (sva + svb) * q2g[qb + d] * ch;
        attn_v[(((size_t)(b_ * NQv + q) * NH) + hh) * 64 + d] = bf16u(ov);
    }
}

// ---------------- Kernel C: MFMA output projection (bf16 A copy) ----------------
__global__ __launch_bounds__(256) void out_proj_kernel(
    const unsigned short* __restrict__ x, const unsigned short* __restrict__ WT,
    const float* __restrict__ bo, float* __restrict__ out)
{
    __shared__ char A_s[64 * 144];
    __shared__ char B_s[64 * 144];

    const int t = threadIdx.x;
    const int r0 = blockIdx.x * 64;
    const int ct = blockIdx.y;

    const int lane = t & 63, wave = t >> 6;
    const int wr = wave >> 1, wc = wave & 1;
    const int lr = lane & 15, lq = lane >> 4;
    const int srow = t >> 2, sc = t & 3;

    f32x4 acc[2][2];
#pragma unroll
    for (int i = 0; i < 2; i++)
#pragma unroll
        for (int j = 0; j < 2; j++) acc[i][j] = (f32x4){0.f, 0.f, 0.f, 0.f};

    const int arow = (r0 + srow < 800) ? (r0 + srow) : 799;

    for (int kk = 0; kk < 8; kk++) {
        const int k0 = kk * 64;
#pragma unroll
        for (int uu = 0; uu < 2; uu++) {
            const int u = sc * 2 + uu;
            uint4 w = *(const uint4*)(x + (size_t)arow * 512 + k0 + u * 8);
            *(uint4*)(A_s + srow * 144 + u * 16) = w;
        }
#pragma unroll
        for (int uu = 0; uu < 2; uu++) {
            const int u = sc * 2 + uu;
            uint4 w = *(const uint4*)(WT + (size_t)(ct * 64 + srow) * 512 + k0 + u * 8);
            *(uint4*)(B_s + srow * 144 + u * 16) = w;
        }
        __syncthreads();
#pragma unroll
        for (int ks = 0; ks < 2; ks++) {
            short8 a0 = *(const short8*)(A_s + (wr * 32 + lr) * 144 + (ks * 4 + lq) * 16);
            short8 a1 = *(const short8*)(A_s + (wr * 32 + 16 + lr) * 144 + (ks * 4 + lq) * 16);
            short8 b0 = *(const short8*)(B_s + (wc * 32 + lr) * 144 + (ks * 4 + lq) * 16);
            short8 b1 = *(const short8*)(B_s + (wc * 32 + 16 + lr) * 144 + (ks * 4 + lq) * 16);
            acc[0][0] = __builtin_amdgcn_mfma_f32_16x16x32_bf16(a0, b0, acc[0][0], 0, 0, 0);
            acc[0][1] = __builtin_amdgcn_mfma_f32_16x16x32_bf16(a0, b1, acc[0][1], 0, 0, 0);
            acc[1][0] = __builtin_amdgcn_mfma_f32_16x16x32_bf16(a1, b0, acc[1][0], 0, 0, 0);
            acc[1][1] = __builtin_amdgcn_mfma_f32_16x16x32_bf16(a1, b1, acc[1][1], 0, 0, 0);
        }
        __syncthreads();
    }

#pragma unroll
    for (int nt = 0; nt < 2; nt++) {
        const int j = ct * 64 + wc * 32 + nt * 16 + lr;
        const float bias = bo[j];
#pragma unroll
        for (int mt = 0; mt < 2; mt++) {
#pragma unroll
            for (int r = 0; r < 4; r++) {
                const int rowg = r0 + wr * 32 + mt * 16 + lq * 4 + r;
                if (rowg < 800) out[(size_t)rowg * 512 + j] = acc[mt][nt][r] + bias;
            }
        }
    }
}

extern "C" void kernel_launch(void* const* d_in, const int* in_sizes, int n_in,
                              void* d_out, int out_size, void* d_ws, size_t ws_size,
                              hipStream_t stream) {
    (void)in_sizes; (void)n_in; (void)out_size; (void)ws_size;
    const float* queries = (const float*)d_in[0];
    const float* keys    = (const float*)d_in[1];
    const float* values  = (const float*)d_in[2];
    const float* W_q1 = (const float*)d_in[3];
    const float* b_q1 = (const float*)d_in[4];
    const float* g_q1w = (const float*)d_in[5];
    const float* g_q1b = (const float*)d_in[6];
    const float* W_q2 = (const float*)d_in[7];
    const float* b_q2 = (const float*)d_in[8];
    const float* g_q2w = (const float*)d_in[9];
    const float* g_q2b = (const float*)d_in[10];
    const float* W_k = (const float*)d_in[11];
    const float* b_k = (const float*)d_in[12];
    const float* g_kw = (const float*)d_in[13];
    const float* g_kb = (const float*)d_in[14];
    const float* W_v = (const float*)d_in[15];
    const float* b_v = (const float*)d_in[16];
    const float* g_vw = (const float*)d_in[17];
    const float* g_vb = (const float*)d_in[18];
    const float* W_m = (const float*)d_in[19];
    const float* b_m = (const float*)d_in[20];
    const float* W_s = (const float*)d_in[21];
    const float* b_s = (const float*)d_in[22];
    const float* W_c = (const float*)d_in[23];
    const float* b_c = (const float*)d_in[24];
    const float* W_o = (const float*)d_in[25];
    const float* b_o = (const float*)d_in[26];

    float* ws = (float*)d_ws;
    const size_t PROJ = (size_t)BSv * NQv * 512;  // 409600 floats
    float* q1 = ws;
    float* q2 = q1 + PROJ;
    float* kk = q2 + PROJ;
    float* vv = kk + PROJ;
    unsigned short* av = (unsigned short*)(vv + PROJ);              // attn_v bf16 [800][512]
    unsigned short* wt = av + PROJ;                                  // 5 x [512][512] bf16
    unsigned int* wcp = (unsigned int*)(wt + (size_t)5 * 512 * 512); // [64][64] packed Wc
    unsigned short* xbf = (unsigned short*)(wcp + 4096);             // 3 x [800][512] bf16

    wt_kernel<<<dim3(8, 8, 9), 256, 0, stream>>>(
        W_q1, W_q2, W_k, W_v, W_o, W_c, queries, keys, values, wt, wcp, xbf);

    proj_kernel<<<dim3(13, 8, 4), 256, 0, stream>>>(
        xbf, wt,
        b_q1, g_q1w, g_q1b,
        b_q2, g_q2w, g_q2b,
        b_k, g_kw, g_kb,
        b_v, g_vw, g_vb,
        q1, q2, kk, vv);

    attn_kernel<<<dim3(4, BSv * NH), 512, 0, stream>>>(
        q1, q2, kk, vv, W_m, b_m, W_s, b_s, wcp, b_c, av);

    out_proj_kernel<<<dim3(13, 8), 256, 0, stream>>>(av, wt + (size_t)4 * 512 * 512, b_o, (float*)d_out);
}